// Round 10
// baseline (218.812 us; speedup 1.0000x reference)
//
#include <hip/hip_runtime.h>
#include <math.h>

#define EPS_F 1e-7f

constexpr int Bc = 32, Tc = 8192, Kc = 16;
constexpr int ROWS     = Bc * Tc;              // 262144 rows
constexpr int BLOCK    = 256;                  // 4 waves
constexpr int NITEM4   = ROWS * 4;             // 1048576 vec4 items
constexpr int ST_ITEMS = 512;                  // items per super-tile
constexpr int NST      = NITEM4 / ST_ITEMS;    // 2048 super-tiles
constexpr int NBLK     = 512;                  // 1 resident/CU, 2 rounds
constexpr int ST_PER_BLK = NST / NBLK;         // 4 super-tiles per block
constexpr int REG_B    = ST_ITEMS * 16;        // 8192 B per array per buffer
constexpr int NARR     = 8;                    // staged 16B/item arrays
constexpr int BUF_B    = NARR * REG_B;         // 64 KB per buffer
// LDS: 2 buffers x 64 KB = 128 KB  (+ reduce scratch)

typedef unsigned long long u64;

__device__ __forceinline__ u64 shflx64(u64 v, int m) {
  unsigned lo = __shfl_xor((unsigned)v, m, 64);
  unsigned hi = __shfl_xor((unsigned)(v >> 32), m, 64);
  return ((u64)hi << 32) | lo;
}

// Async global->LDS DMA: LDS dest is wave-uniform base (HW adds lane*size);
// global src is per-lane. Zero VGPR cost -> compiler cannot chunk the burst
// (the R7/R8/R9 failure mode).
__device__ __forceinline__ void dma16(void* lds, const void* g) {
  __builtin_amdgcn_global_load_lds(
      (const __attribute__((address_space(1))) void*)g,
      (__attribute__((address_space(3))) void*)lds, 16, 0, 0);
}

#define WAITCNT_VM(N)                                                      \
  do {                                                                     \
    asm volatile("s_waitcnt vmcnt(" #N ")" ::: "memory");                  \
    __builtin_amdgcn_sched_barrier(0);                                     \
  } while (0)

struct Ptrs {
  const char* a16[NARR];   // ocid, ocan, ofire, ovalid, cid, live, trig, valp
  const char* clog;
  const char* wscore;
  const char* oshw;
};

// ARRAY-MAJOR staging: all 16 DMAs of a super-tile grouped by array, so each
// array receives one contiguous 8KB run per CU (4 waves x 2 bursts clustered
// in time) instead of a 1KB 11-way round-robin. Targets DRAM page locality
// -> lower miss latency -> higher per-CU BW under the fixed MSHR budget.
__device__ __forceinline__ void stage(char* buf, const Ptrs& P, int T,
                                      int w, int lane) {
  #pragma unroll
  for (int a = 0; a < NARR; ++a) {
    const char* g = P.a16[a];
    char* r = buf + a * REG_B + w * 1024;
    dma16(r + 0 * 4096, g + (size_t)(T + 0 * 256 + w * 64 + lane) * 16);
    dma16(r + 1 * 4096, g + (size_t)(T + 1 * 256 + w * 64 + lane) * 16);
  }
}

// Proven compute path (absmax=0.0 in R2/R4/R7/R8/R9), fed from LDS + direct
// clog/row-scalar loads for one item gi.
__device__ __forceinline__ void compute_item(
    const char* buf, int u, int tid, int lane, int gi, const Ptrs& P,
    float a[6])
{
  const int ib = u * 4096 + tid * 16;
  const int4   oc = *(const int4*)  (buf + 0 * REG_B + ib);
  const int4   cc = *(const int4*)  (buf + 1 * REG_B + ib);
  const float4 ff = *(const float4*)(buf + 2 * REG_B + ib);
  const float4 vv = *(const float4*)(buf + 3 * REG_B + ib);
  const int4   cd = *(const int4*)  (buf + 4 * REG_B + ib);
  const int4   lm = *(const int4*)  (buf + 5 * REG_B + ib);
  const float4 ph = *(const float4*)(buf + 6 * REG_B + ib);
  const float4 pq = *(const float4*)(buf + 7 * REG_B + ib);
  const size_t o48 = (size_t)gi * 48;
  const float4 lA = *(const float4*)(P.clog + o48 + 0);
  const float4 lB = *(const float4*)(P.clog + o48 + 16);
  const float4 lC = *(const float4*)(P.clog + o48 + 32);
  const int row = gi >> 2;
  const float wx = *(const float*)(P.wscore + (size_t)row * 4);
  const float wy = *(const float*)(P.oshw   + (size_t)row * 4);

  u64 tblLo = 0ull, tblHi = 0ull, fndLo = 0ull, fndHi = 0ull;
  {
    const int   ocs[4] = {oc.x, oc.y, oc.z, oc.w};
    const int   ccs[4] = {cc.x, cc.y, cc.z, cc.w};
    const float ffs[4] = {ff.x, ff.y, ff.z, ff.w};
    const float vvs[4] = {vv.x, vv.y, vv.z, vv.w};
    #pragma unroll
    for (int j = 0; j < 4; ++j) {
      const unsigned c  = (unsigned)ocs[j] & 31u;
      const unsigned sh = (c & 15u) * 4u;
      const bool isLo   = c < 16u;
      const bool seen   = (((isLo ? fndLo : fndHi) >> sh) & 1ull) != 0ull;
      const unsigned nib = (unsigned)ffs[j] | ((unsigned)vvs[j] << 1) |
                           ((unsigned)ccs[j] << 2);
      const u64 add  = seen ? 0ull : ((u64)nib << sh);
      const u64 fadd = 0xFull << sh;
      tblLo |= isLo ? add : 0ull;
      tblHi |= isLo ? 0ull : add;
      fndLo |= isLo ? fadd : 0ull;
      fndHi |= isLo ? 0ull : fadd;
    }
  }

  #pragma unroll
  for (int m = 1; m <= 2; m <<= 1) {
    const u64 pTL = shflx64(tblLo, m);
    const u64 pTH = shflx64(tblHi, m);
    const u64 pFL = shflx64(fndLo, m);
    const u64 pFH = shflx64(fndHi, m);
    const bool iLow = (lane & m) == 0;
    const u64 loTL = iLow ? tblLo : pTL, hiTL = iLow ? pTL : tblLo;
    const u64 loTH = iLow ? tblHi : pTH, hiTH = iLow ? pTH : tblHi;
    const u64 loFL = iLow ? fndLo : pFL, hiFL = iLow ? pFL : fndLo;
    const u64 loFH = iLow ? fndHi : pFH, hiFH = iLow ? pFH : fndHi;
    tblLo = loTL | (hiTL & ~loFL);
    tblHi = loTH | (hiTH & ~loFH);
    fndLo = loFL | hiFL;
    fndHi = loFH | hiFH;
  }

  {
    const int   cds[4] = {cd.x, cd.y, cd.z, cd.w};
    const int   lms[4] = {lm.x, lm.y, lm.z, lm.w};
    const float phs[4] = {ph.x, ph.y, ph.z, ph.w};
    const float pqs[4] = {pq.x, pq.y, pq.z, pq.w};
    const float L0[4] = {lA.x, lA.w, lB.z, lC.y};
    const float L1[4] = {lA.y, lB.x, lB.w, lC.z};
    const float L2[4] = {lA.z, lB.y, lC.x, lC.w};
    #pragma unroll
    for (int j = 0; j < 4; ++j) {
      const unsigned c  = (unsigned)cds[j] & 31u;
      const unsigned sh = (c & 15u) * 4u;
      const bool isLo   = c < 16u;
      const bool fnd = (c != 0u) &&
                       ((((isLo ? fndLo : fndHi) >> sh) & 1ull) != 0ull);
      unsigned nib = (unsigned)(((isLo ? tblLo : tblHi) >> sh)) & 15u;
      nib = fnd ? nib : 0u;
      const float fire_t = (float)(nib & 1u);
      const float val_t  = (float)((nib >> 1) & 1u);
      const int   can_t  = (int)(nib >> 2);

      const float m = lms[j] ? 1.f : 0.f;

      const float p  = fminf(fmaxf(phs[j], EPS_F), 1.f - EPS_F);
      const float bf = -__logf((fire_t != 0.f) ? p : 1.f - p);
      const float q  = fminf(fmaxf(pqs[j], EPS_F), 1.f - EPS_F);
      const float bv = -__logf((val_t != 0.f) ? q : 1.f - q);

      const float has = (can_t > 0 && lms[j]) ? 1.f : 0.f;
      const int tgt = (can_t - 1) < 0 ? 0 : (can_t - 1);
      const float l0 = L0[j], l1 = L1[j], l2 = L2[j];
      const float mx  = fmaxf(l0, fmaxf(l1, l2));
      const float lse = mx + __logf(__expf(l0 - mx) + __expf(l1 - mx) +
                                    __expf(l2 - mx));
      const float lt  = (tgt == 0) ? l0 : ((tgt == 1) ? l1 : l2);

      a[0] += bf * m;
      a[1] += m;
      a[2] += (lse - lt) * has;
      a[3] += has;
      a[4] += bv * m;
    }
  }

  if ((tid & 3) == 0) {
    a[5] += fmaxf(wx, 0.f) - wx * wy + __logf(1.f + __expf(-fabsf(wx)));
  }
}

__global__ __launch_bounds__(BLOCK) void loss_main(
    const float* __restrict__ trig,
    const float* __restrict__ valp,
    const float* __restrict__ clog,
    const float* __restrict__ wscore,
    const int*   __restrict__ live,
    const int*   __restrict__ cid,
    const float* __restrict__ ofire,
    const int*   __restrict__ ocan,
    const float* __restrict__ ovalid,
    const float* __restrict__ oshw,
    const int*   __restrict__ ocid,
    float* __restrict__ part)            // [NBLK][6]
{
  __shared__ __align__(16) char smem[2 * BUF_B];   // 128 KB -> 1 block/CU

  const int tid  = threadIdx.x;
  const int lane = tid & 63;
  const int w    = tid >> 6;
  const int T0   = blockIdx.x * (ST_PER_BLK * ST_ITEMS);

  Ptrs P;
  P.a16[0] = (const char*)ocid;  P.a16[1] = (const char*)ocan;
  P.a16[2] = (const char*)ofire; P.a16[3] = (const char*)ovalid;
  P.a16[4] = (const char*)cid;   P.a16[5] = (const char*)live;
  P.a16[6] = (const char*)trig;  P.a16[7] = (const char*)valp;
  P.clog   = (const char*)clog;
  P.wscore = (const char*)wscore;
  P.oshw   = (const char*)oshw;

  float a[6] = {0.f, 0.f, 0.f, 0.f, 0.f, 0.f};

  // prologue: stage super-tile 0 (16 DMAs per wave, array-major)
  stage(smem, P, T0, w, lane);

  for (int s = 0; s < ST_PER_BLK; ++s) {
    char* buf = smem + (s & 1) * BUF_B;
    if (s + 1 < ST_PER_BLK) {
      // WAR guard: ds_reads against the buffer we're about to overwrite
      // retired (they were consumed 2 super-tiles ago; near-free).
      asm volatile("s_waitcnt lgkmcnt(0)" ::: "memory");
      stage(smem + ((s + 1) & 1) * BUF_B, P, T0 + (s + 1) * ST_ITEMS, w, lane);
      WAITCNT_VM(16);   // tile s landed; tile s+1's 16 DMAs stay in flight
                        // (older clog direct-loads drain first: in-order)
    } else {
      WAITCNT_VM(0);
    }
    const int T = T0 + s * ST_ITEMS;
    compute_item(buf, 0, tid, lane, T + 0 * 256 + tid, P, a);
    compute_item(buf, 1, tid, lane, T + 1 * 256 + tid, P, a);
  }

  // ---- wave reduce, then block reduce via LDS (only barrier in the kernel)
  #pragma unroll
  for (int off = 32; off > 0; off >>= 1) {
    #pragma unroll
    for (int i = 0; i < 6; ++i) a[i] += __shfl_down(a[i], off, 64);
  }
  __shared__ float red[4][6];
  if (lane == 0) {
    #pragma unroll
    for (int i = 0; i < 6; ++i) red[w][i] = a[i];
  }
  __syncthreads();
  if (tid == 0) {
    #pragma unroll
    for (int i = 0; i < 6; ++i)
      part[blockIdx.x * 6 + i] = red[0][i] + red[1][i] + red[2][i] + red[3][i];
  }
}

// Reduce NBLK partials in double, compute the 5 outputs.
__global__ __launch_bounds__(BLOCK) void loss_finalize(
    const float* __restrict__ part, float* __restrict__ out)
{
  double v[6] = {0, 0, 0, 0, 0, 0};
  for (int r = threadIdx.x; r < NBLK; r += BLOCK) {
    #pragma unroll
    for (int i = 0; i < 6; ++i) v[i] += (double)part[r * 6 + i];
  }
  #pragma unroll
  for (int off = 32; off > 0; off >>= 1) {
    #pragma unroll
    for (int i = 0; i < 6; ++i) v[i] += __shfl_down(v[i], off, 64);
  }
  __shared__ double red[4][6];
  const int w = threadIdx.x >> 6, lane = threadIdx.x & 63;
  if (lane == 0) {
    #pragma unroll
    for (int i = 0; i < 6; ++i) red[w][i] = v[i];
  }
  __syncthreads();
  if (threadIdx.x == 0) {
    double a[6];
    #pragma unroll
    for (int i = 0; i < 6; ++i) a[i] = red[0][i] + red[1][i] + red[2][i] + red[3][i];
    const double live_n = a[1] < 1.0 ? 1.0 : a[1];
    const double fire   = a[0] / live_n;                                   // LAM_FIRE   = 1.0
    const double cancel = (a[3] > 0.0) ? a[2] / (a[3] < 1.0 ? 1.0 : a[3])  // LAM_CANCEL = 1.0
                                       : 0.0;
    const double valid  = 0.5 * a[4] / live_n;                             // LAM_VALID  = 0.5
    const double wr     = 0.5 * a[5] / (double)ROWS;                       // LAM_WRITE  = 0.5
    out[0] = (float)fire;
    out[1] = (float)cancel;
    out[2] = (float)valid;
    out[3] = (float)wr;
    out[4] = (float)(fire + cancel + valid + wr);
  }
}

extern "C" void kernel_launch(void* const* d_in, const int* in_sizes, int n_in,
                              void* d_out, int out_size, void* d_ws, size_t ws_size,
                              hipStream_t stream) {
  const float* trig   = (const float*)d_in[0];
  const float* valp   = (const float*)d_in[1];
  const float* clog   = (const float*)d_in[2];
  const float* wscore = (const float*)d_in[3];
  const int*   live   = (const int*)  d_in[4];
  const int*   cid    = (const int*)  d_in[5];
  const float* ofire  = (const float*)d_in[6];
  const int*   ocan   = (const int*)  d_in[7];
  const float* ovalid = (const float*)d_in[8];
  const float* oshw   = (const float*)d_in[9];
  const int*   ocid   = (const int*)  d_in[10];
  float* out  = (float*)d_out;
  float* part = (float*)d_ws;   // NBLK*6 floats = 12 KB, fully overwritten

  loss_main<<<NBLK, BLOCK, 0, stream>>>(trig, valp, clog, wscore, live, cid,
                                        ofire, ocan, ovalid, oshw, ocid, part);
  loss_finalize<<<1, BLOCK, 0, stream>>>(part, out);
}

// Round 11
// 190.972 us; speedup vs baseline: 1.1458x; 1.1458x over previous
//
#include <hip/hip_runtime.h>
#include <math.h>

#define EPS_F 1e-7f

constexpr int Bc = 32, Tc = 8192, Kc = 16;
constexpr int ROWS   = Bc * Tc;            // 262144 rows
constexpr int BLOCK  = 256;
constexpr int NITEM4 = ROWS * 4;           // 1048576 vec4 items (4 slots each)
constexpr int NBLK   = NITEM4 / BLOCK;     // 4096 blocks, 1 item per thread

typedef unsigned long long u64;
typedef float __attribute__((ext_vector_type(4))) f32x4;
typedef int   __attribute__((ext_vector_type(4))) i32x4;

__device__ __forceinline__ u64 shflx64(u64 v, int m) {
  unsigned lo = __shfl_xor((unsigned)v, m, 64);
  unsigned hi = __shfl_xor((unsigned)(v >> 32), m, 64);
  return ((u64)hi << 32) | lo;
}

// Non-temporal (evict-first / streaming) loads: zero reuse in this kernel,
// so lines should NOT allocate into L2/L3. Tests the cache-allocation-
// pressure theory of the 2.7 TB/s service cap (R2..R10 all converge there
// with allocating loads; FETCH=91MB shows L3 half-thrashes each iteration).
__device__ __forceinline__ i32x4 ntld_i4(const void* p) {
  return __builtin_nontemporal_load((const i32x4*)p);
}
__device__ __forceinline__ f32x4 ntld_f4(const void* p) {
  return __builtin_nontemporal_load((const f32x4*)p);
}
__device__ __forceinline__ float ntld_f(const float* p) {
  return __builtin_nontemporal_load(p);
}

// Item-per-thread streaming (R7 structure, 70.1us, absmax=0.0): lane i owns
// vec4-item (base+i) -> every load is a dense 1KB/wave coalesced burst.
// Per-row oracle table via the proven 4-lane shuffle merge. No LDS staging,
// no barriers in the stream.
__global__ __launch_bounds__(BLOCK) void loss_main(
    const float* __restrict__ trig,
    const float* __restrict__ valp,
    const float* __restrict__ clog,
    const float* __restrict__ wscore,
    const int*   __restrict__ live,
    const int*   __restrict__ cid,
    const float* __restrict__ ofire,
    const int*   __restrict__ ocan,
    const float* __restrict__ ovalid,
    const float* __restrict__ oshw,
    const int*   __restrict__ ocid,
    float* __restrict__ part)            // [NBLK][6]
{
  const int tid  = threadIdx.x;
  const int lane = tid & 63;
  const int gi   = blockIdx.x * BLOCK + tid;      // my vec4 item
  const size_t o16 = (size_t)gi * 16;
  const size_t o48 = (size_t)gi * 48;

  // ---- coalesced register-direct NT loads (13 vec4 + 2 scalar per lane)
  const i32x4 oc = ntld_i4((const char*)ocid   + o16);
  const i32x4 cc = ntld_i4((const char*)ocan   + o16);
  const f32x4 ff = ntld_f4((const char*)ofire  + o16);
  const f32x4 vv = ntld_f4((const char*)ovalid + o16);
  const i32x4 cd = ntld_i4((const char*)cid    + o16);
  const i32x4 lm = ntld_i4((const char*)live   + o16);
  const f32x4 ph = ntld_f4((const char*)trig   + o16);
  const f32x4 pq = ntld_f4((const char*)valp   + o16);
  const f32x4 lA = ntld_f4((const char*)clog   + o48 + 0);
  const f32x4 lB = ntld_f4((const char*)clog   + o48 + 16);
  const f32x4 lC = ntld_f4((const char*)clog   + o48 + 32);
  const int row = gi >> 2;
  const float wx = ntld_f(wscore + row);
  const float wy = ntld_f(oshw   + row);

  // ---- per-lane partial oracle table (my 4 slots, slot order; first wins)
  u64 tblLo = 0ull, tblHi = 0ull, fndLo = 0ull, fndHi = 0ull;
  #pragma unroll
  for (int j = 0; j < 4; ++j) {
    const unsigned c  = (unsigned)oc[j] & 31u;
    const unsigned sh = (c & 15u) * 4u;
    const bool isLo   = c < 16u;
    const bool seen   = (((isLo ? fndLo : fndHi) >> sh) & 1ull) != 0ull;
    const unsigned nib = (unsigned)ff[j] | ((unsigned)vv[j] << 1) |
                         ((unsigned)cc[j] << 2);
    const u64 add  = seen ? 0ull : ((u64)nib << sh);
    const u64 fadd = 0xFull << sh;
    tblLo |= isLo ? add : 0ull;
    tblHi |= isLo ? 0ull : add;
    fndLo |= isLo ? fadd : 0ull;
    fndHi |= isLo ? 0ull : fadd;
  }

  // ---- merge across the 4-lane row group (lower lane = earlier slot wins)
  #pragma unroll
  for (int m = 1; m <= 2; m <<= 1) {
    const u64 pTL = shflx64(tblLo, m);
    const u64 pTH = shflx64(tblHi, m);
    const u64 pFL = shflx64(fndLo, m);
    const u64 pFH = shflx64(fndHi, m);
    const bool iLow = (lane & m) == 0;
    const u64 loTL = iLow ? tblLo : pTL, hiTL = iLow ? pTL : tblLo;
    const u64 loTH = iLow ? tblHi : pTH, hiTH = iLow ? pTH : tblHi;
    const u64 loFL = iLow ? fndLo : pFL, hiFL = iLow ? pFL : fndLo;
    const u64 loFH = iLow ? fndHi : pFH, hiFH = iLow ? pFH : fndHi;
    tblLo = loTL | (hiTL & ~loFL);
    tblHi = loTH | (hiTH & ~loFH);
    fndLo = loFL | hiFL;
    fndHi = loFH | hiFH;
  }

  // ---- losses for my 4 slots (proven compute path, unchanged)
  float a0 = 0.f, a1 = 0.f, a2 = 0.f, a3 = 0.f, a4 = 0.f;
  {
    const float L0[4] = {lA[0], lA[3], lB[2], lC[1]};
    const float L1[4] = {lA[1], lB[0], lB[3], lC[2]};
    const float L2[4] = {lA[2], lB[1], lC[0], lC[3]};
    #pragma unroll
    for (int j = 0; j < 4; ++j) {
      const unsigned c  = (unsigned)cd[j] & 31u;
      const unsigned sh = (c & 15u) * 4u;
      const bool isLo   = c < 16u;
      const bool fnd = (c != 0u) &&
                       ((((isLo ? fndLo : fndHi) >> sh) & 1ull) != 0ull);
      unsigned nib = (unsigned)(((isLo ? tblLo : tblHi) >> sh)) & 15u;
      nib = fnd ? nib : 0u;
      const float fire_t = (float)(nib & 1u);
      const float val_t  = (float)((nib >> 1) & 1u);
      const int   can_t  = (int)(nib >> 2);

      const float m = lm[j] ? 1.f : 0.f;

      const float p  = fminf(fmaxf(ph[j], EPS_F), 1.f - EPS_F);
      const float bf = -__logf((fire_t != 0.f) ? p : 1.f - p);
      const float q  = fminf(fmaxf(pq[j], EPS_F), 1.f - EPS_F);
      const float bv = -__logf((val_t != 0.f) ? q : 1.f - q);

      const float has = (can_t > 0 && lm[j]) ? 1.f : 0.f;
      const int tgt = (can_t - 1) < 0 ? 0 : (can_t - 1);
      const float l0 = L0[j], l1 = L1[j], l2 = L2[j];
      const float mx  = fmaxf(l0, fmaxf(l1, l2));
      const float lse = mx + __logf(__expf(l0 - mx) + __expf(l1 - mx) +
                                    __expf(l2 - mx));
      const float lt  = (tgt == 0) ? l0 : ((tgt == 1) ? l1 : l2);

      a0 += bf * m;
      a1 += m;
      a2 += (lse - lt) * has;
      a3 += has;
      a4 += bv * m;
    }
  }

  // ---- write term (one lane per row adds it)
  float a5 = 0.f;
  if ((tid & 3) == 0) {
    a5 = fmaxf(wx, 0.f) - wx * wy + __logf(1.f + __expf(-fabsf(wx)));
  }

  // ---- wave reduce, then block reduce via LDS
  float v[6] = {a0, a1, a2, a3, a4, a5};
  #pragma unroll
  for (int off = 32; off > 0; off >>= 1) {
    #pragma unroll
    for (int i = 0; i < 6; ++i) v[i] += __shfl_down(v[i], off, 64);
  }
  __shared__ float red[4][6];
  const int w = tid >> 6;
  if (lane == 0) {
    #pragma unroll
    for (int i = 0; i < 6; ++i) red[w][i] = v[i];
  }
  __syncthreads();
  if (tid == 0) {
    #pragma unroll
    for (int i = 0; i < 6; ++i)
      part[blockIdx.x * 6 + i] = red[0][i] + red[1][i] + red[2][i] + red[3][i];
  }
}

// Reduce NBLK partials in double, compute the 5 outputs.
__global__ __launch_bounds__(BLOCK) void loss_finalize(
    const float* __restrict__ part, float* __restrict__ out)
{
  double v[6] = {0, 0, 0, 0, 0, 0};
  for (int r = threadIdx.x; r < NBLK; r += BLOCK) {
    #pragma unroll
    for (int i = 0; i < 6; ++i) v[i] += (double)part[r * 6 + i];
  }
  #pragma unroll
  for (int off = 32; off > 0; off >>= 1) {
    #pragma unroll
    for (int i = 0; i < 6; ++i) v[i] += __shfl_down(v[i], off, 64);
  }
  __shared__ double red[4][6];
  const int w = threadIdx.x >> 6, lane = threadIdx.x & 63;
  if (lane == 0) {
    #pragma unroll
    for (int i = 0; i < 6; ++i) red[w][i] = v[i];
  }
  __syncthreads();
  if (threadIdx.x == 0) {
    double a[6];
    #pragma unroll
    for (int i = 0; i < 6; ++i) a[i] = red[0][i] + red[1][i] + red[2][i] + red[3][i];
    const double live_n = a[1] < 1.0 ? 1.0 : a[1];
    const double fire   = a[0] / live_n;                                   // LAM_FIRE   = 1.0
    const double cancel = (a[3] > 0.0) ? a[2] / (a[3] < 1.0 ? 1.0 : a[3])  // LAM_CANCEL = 1.0
                                       : 0.0;
    const double valid  = 0.5 * a[4] / live_n;                             // LAM_VALID  = 0.5
    const double wr     = 0.5 * a[5] / (double)ROWS;                       // LAM_WRITE  = 0.5
    out[0] = (float)fire;
    out[1] = (float)cancel;
    out[2] = (float)valid;
    out[3] = (float)wr;
    out[4] = (float)(fire + cancel + valid + wr);
  }
}

extern "C" void kernel_launch(void* const* d_in, const int* in_sizes, int n_in,
                              void* d_out, int out_size, void* d_ws, size_t ws_size,
                              hipStream_t stream) {
  const float* trig   = (const float*)d_in[0];
  const float* valp   = (const float*)d_in[1];
  const float* clog   = (const float*)d_in[2];
  const float* wscore = (const float*)d_in[3];
  const int*   live   = (const int*)  d_in[4];
  const int*   cid    = (const int*)  d_in[5];
  const float* ofire  = (const float*)d_in[6];
  const int*   ocan   = (const int*)  d_in[7];
  const float* ovalid = (const float*)d_in[8];
  const float* oshw   = (const float*)d_in[9];
  const int*   ocid   = (const int*)  d_in[10];
  float* out  = (float*)d_out;
  float* part = (float*)d_ws;   // NBLK*6 floats = 96 KB, fully overwritten

  loss_main<<<NBLK, BLOCK, 0, stream>>>(trig, valp, clog, wscore, live, cid,
                                        ofire, ocan, ovalid, oshw, ocid, part);
  loss_finalize<<<1, BLOCK, 0, stream>>>(part, out);
}

// Round 12
// 189.434 us; speedup vs baseline: 1.1551x; 1.0081x over previous
//
#include <hip/hip_runtime.h>
#include <math.h>

#define EPS_F 1e-7f

constexpr int Bc = 32, Tc = 8192, Kc = 16;
constexpr int ROWS   = Bc * Tc;            // 262144 rows
constexpr int BLOCK  = 256;
constexpr int NITEM4 = ROWS * 4;           // 1048576 vec4 items (4 slots each)
constexpr int UNROLL = 2;                  // items per thread
constexpr int NBLK   = NITEM4 / (BLOCK * UNROLL);  // 2048 blocks

typedef unsigned long long u64;
typedef float __attribute__((ext_vector_type(4))) f32x4;
typedef int   __attribute__((ext_vector_type(4))) i32x4;

__device__ __forceinline__ u64 shflx64(u64 v, int m) {
  unsigned lo = __shfl_xor((unsigned)v, m, 64);
  unsigned hi = __shfl_xor((unsigned)(v >> 32), m, 64);
  return ((u64)hi << 32) | lo;
}

// Non-temporal loads (R11 win, -20us): no L2/L3 allocation for zero-reuse
// streams -> service rate 2.7 -> 3.7 TB/s. Keep everywhere.
__device__ __forceinline__ i32x4 ntld_i4(const void* p) {
  return __builtin_nontemporal_load((const i32x4*)p);
}
__device__ __forceinline__ f32x4 ntld_f4(const void* p) {
  return __builtin_nontemporal_load((const f32x4*)p);
}
__device__ __forceinline__ float ntld_f(const float* p) {
  return __builtin_nontemporal_load(p);
}

struct Item {
  i32x4 oc, cc, cd, lm;
  f32x4 ff, vv, ph, pq, lA, lB, lC;
  float wx, wy;
};

__device__ __forceinline__ void load_item(
    Item& T, int gi,
    const char* trig, const char* valp, const char* clog, const float* wscore,
    const char* live, const char* cid, const char* ofire, const char* ocan,
    const char* ovalid, const float* oshw, const char* ocid)
{
  const size_t o16 = (size_t)gi * 16;
  const size_t o48 = (size_t)gi * 48;
  T.oc = ntld_i4(ocid   + o16);
  T.cc = ntld_i4(ocan   + o16);
  T.ff = ntld_f4(ofire  + o16);
  T.vv = ntld_f4(ovalid + o16);
  T.cd = ntld_i4(cid    + o16);
  T.lm = ntld_i4(live   + o16);
  T.ph = ntld_f4(trig   + o16);
  T.pq = ntld_f4(valp   + o16);
  T.lA = ntld_f4(clog   + o48 + 0);
  T.lB = ntld_f4(clog   + o48 + 16);
  T.lC = ntld_f4(clog   + o48 + 32);
  const int row = gi >> 2;
  T.wx = ntld_f(wscore + row);
  T.wy = ntld_f(oshw   + row);
}

// Proven compute path (absmax=0.0 in R2/R4/R7..R11).
__device__ __forceinline__ void compute_item(
    const Item& T, int tid, int lane, float a[6])
{
  u64 tblLo = 0ull, tblHi = 0ull, fndLo = 0ull, fndHi = 0ull;
  #pragma unroll
  for (int j = 0; j < 4; ++j) {
    const unsigned c  = (unsigned)T.oc[j] & 31u;
    const unsigned sh = (c & 15u) * 4u;
    const bool isLo   = c < 16u;
    const bool seen   = (((isLo ? fndLo : fndHi) >> sh) & 1ull) != 0ull;
    const unsigned nib = (unsigned)T.ff[j] | ((unsigned)T.vv[j] << 1) |
                         ((unsigned)T.cc[j] << 2);
    const u64 add  = seen ? 0ull : ((u64)nib << sh);
    const u64 fadd = 0xFull << sh;
    tblLo |= isLo ? add : 0ull;
    tblHi |= isLo ? 0ull : add;
    fndLo |= isLo ? fadd : 0ull;
    fndHi |= isLo ? 0ull : fadd;
  }

  #pragma unroll
  for (int m = 1; m <= 2; m <<= 1) {
    const u64 pTL = shflx64(tblLo, m);
    const u64 pTH = shflx64(tblHi, m);
    const u64 pFL = shflx64(fndLo, m);
    const u64 pFH = shflx64(fndHi, m);
    const bool iLow = (lane & m) == 0;
    const u64 loTL = iLow ? tblLo : pTL, hiTL = iLow ? pTL : tblLo;
    const u64 loTH = iLow ? tblHi : pTH, hiTH = iLow ? pTH : tblHi;
    const u64 loFL = iLow ? fndLo : pFL, hiFL = iLow ? pFL : fndLo;
    const u64 loFH = iLow ? fndHi : pFH, hiFH = iLow ? pFH : fndHi;
    tblLo = loTL | (hiTL & ~loFL);
    tblHi = loTH | (hiTH & ~loFH);
    fndLo = loFL | hiFL;
    fndHi = loFH | hiFH;
  }

  {
    const float L0[4] = {T.lA[0], T.lA[3], T.lB[2], T.lC[1]};
    const float L1[4] = {T.lA[1], T.lB[0], T.lB[3], T.lC[2]};
    const float L2[4] = {T.lA[2], T.lB[1], T.lC[0], T.lC[3]};
    #pragma unroll
    for (int j = 0; j < 4; ++j) {
      const unsigned c  = (unsigned)T.cd[j] & 31u;
      const unsigned sh = (c & 15u) * 4u;
      const bool isLo   = c < 16u;
      const bool fnd = (c != 0u) &&
                       ((((isLo ? fndLo : fndHi) >> sh) & 1ull) != 0ull);
      unsigned nib = (unsigned)(((isLo ? tblLo : tblHi) >> sh)) & 15u;
      nib = fnd ? nib : 0u;
      const float fire_t = (float)(nib & 1u);
      const float val_t  = (float)((nib >> 1) & 1u);
      const int   can_t  = (int)(nib >> 2);

      const float m = T.lm[j] ? 1.f : 0.f;

      const float p  = fminf(fmaxf(T.ph[j], EPS_F), 1.f - EPS_F);
      const float bf = -__logf((fire_t != 0.f) ? p : 1.f - p);
      const float q  = fminf(fmaxf(T.pq[j], EPS_F), 1.f - EPS_F);
      const float bv = -__logf((val_t != 0.f) ? q : 1.f - q);

      const float has = (can_t > 0 && T.lm[j]) ? 1.f : 0.f;
      const int tgt = (can_t - 1) < 0 ? 0 : (can_t - 1);
      const float l0 = L0[j], l1 = L1[j], l2 = L2[j];
      const float mx  = fmaxf(l0, fmaxf(l1, l2));
      const float lse = mx + __logf(__expf(l0 - mx) + __expf(l1 - mx) +
                                    __expf(l2 - mx));
      const float lt  = (tgt == 0) ? l0 : ((tgt == 1) ? l1 : l2);

      a[0] += bf * m;
      a[1] += m;
      a[2] += (lse - lt) * has;
      a[3] += has;
      a[4] += bv * m;
    }
  }

  if ((tid & 3) == 0) {
    a[5] += fmaxf(T.wx, 0.f) - T.wx * T.wy +
            __logf(1.f + __expf(-fabsf(T.wx)));
  }
}

// R11 structure + 2 items/thread: both items' 26 NT loads are issued before
// either compute (named A/B, static indexing - rule #20), doubling per-wave
// bytes in flight. Discriminates ILP-limited (improves) vs vmem-issue-rate-
// limited (flat) now that NT removed the cache-allocation cap.
__global__ __launch_bounds__(BLOCK) void loss_main(
    const float* __restrict__ trig,
    const float* __restrict__ valp,
    const float* __restrict__ clog,
    const float* __restrict__ wscore,
    const int*   __restrict__ live,
    const int*   __restrict__ cid,
    const float* __restrict__ ofire,
    const int*   __restrict__ ocan,
    const float* __restrict__ ovalid,
    const float* __restrict__ oshw,
    const int*   __restrict__ ocid,
    float* __restrict__ part)            // [NBLK][6]
{
  const int tid  = threadIdx.x;
  const int lane = tid & 63;
  const int gi0  = blockIdx.x * (BLOCK * UNROLL) + tid;
  const int gi1  = gi0 + BLOCK;

  const char* trig_b  = (const char*)trig;
  const char* valp_b  = (const char*)valp;
  const char* clog_b  = (const char*)clog;
  const char* live_b  = (const char*)live;
  const char* cid_b   = (const char*)cid;
  const char* ofire_b = (const char*)ofire;
  const char* ocan_b  = (const char*)ocan;
  const char* oval_b  = (const char*)ovalid;
  const char* ocid_b  = (const char*)ocid;

  Item A, B;
  load_item(A, gi0, trig_b, valp_b, clog_b, wscore, live_b, cid_b,
            ofire_b, ocan_b, oval_b, oshw, ocid_b);
  load_item(B, gi1, trig_b, valp_b, clog_b, wscore, live_b, cid_b,
            ofire_b, ocan_b, oval_b, oshw, ocid_b);

  float a[6] = {0.f, 0.f, 0.f, 0.f, 0.f, 0.f};
  compute_item(A, tid, lane, a);
  compute_item(B, tid, lane, a);

  // ---- wave reduce, then block reduce via LDS
  #pragma unroll
  for (int off = 32; off > 0; off >>= 1) {
    #pragma unroll
    for (int i = 0; i < 6; ++i) a[i] += __shfl_down(a[i], off, 64);
  }
  __shared__ float red[4][6];
  const int w = tid >> 6;
  if (lane == 0) {
    #pragma unroll
    for (int i = 0; i < 6; ++i) red[w][i] = a[i];
  }
  __syncthreads();
  if (tid == 0) {
    #pragma unroll
    for (int i = 0; i < 6; ++i)
      part[blockIdx.x * 6 + i] = red[0][i] + red[1][i] + red[2][i] + red[3][i];
  }
}

// Reduce NBLK partials in double, compute the 5 outputs.
__global__ __launch_bounds__(BLOCK) void loss_finalize(
    const float* __restrict__ part, float* __restrict__ out)
{
  double v[6] = {0, 0, 0, 0, 0, 0};
  for (int r = threadIdx.x; r < NBLK; r += BLOCK) {
    #pragma unroll
    for (int i = 0; i < 6; ++i) v[i] += (double)part[r * 6 + i];
  }
  #pragma unroll
  for (int off = 32; off > 0; off >>= 1) {
    #pragma unroll
    for (int i = 0; i < 6; ++i) v[i] += __shfl_down(v[i], off, 64);
  }
  __shared__ double red[4][6];
  const int w = threadIdx.x >> 6, lane = threadIdx.x & 63;
  if (lane == 0) {
    #pragma unroll
    for (int i = 0; i < 6; ++i) red[w][i] = v[i];
  }
  __syncthreads();
  if (threadIdx.x == 0) {
    double a[6];
    #pragma unroll
    for (int i = 0; i < 6; ++i) a[i] = red[0][i] + red[1][i] + red[2][i] + red[3][i];
    const double live_n = a[1] < 1.0 ? 1.0 : a[1];
    const double fire   = a[0] / live_n;                                   // LAM_FIRE   = 1.0
    const double cancel = (a[3] > 0.0) ? a[2] / (a[3] < 1.0 ? 1.0 : a[3])  // LAM_CANCEL = 1.0
                                       : 0.0;
    const double valid  = 0.5 * a[4] / live_n;                             // LAM_VALID  = 0.5
    const double wr     = 0.5 * a[5] / (double)ROWS;                       // LAM_WRITE  = 0.5
    out[0] = (float)fire;
    out[1] = (float)cancel;
    out[2] = (float)valid;
    out[3] = (float)wr;
    out[4] = (float)(fire + cancel + valid + wr);
  }
}

extern "C" void kernel_launch(void* const* d_in, const int* in_sizes, int n_in,
                              void* d_out, int out_size, void* d_ws, size_t ws_size,
                              hipStream_t stream) {
  const float* trig   = (const float*)d_in[0];
  const float* valp   = (const float*)d_in[1];
  const float* clog   = (const float*)d_in[2];
  const float* wscore = (const float*)d_in[3];
  const int*   live   = (const int*)  d_in[4];
  const int*   cid    = (const int*)  d_in[5];
  const float* ofire  = (const float*)d_in[6];
  const int*   ocan   = (const int*)  d_in[7];
  const float* ovalid = (const float*)d_in[8];
  const float* oshw   = (const float*)d_in[9];
  const int*   ocid   = (const int*)  d_in[10];
  float* out  = (float*)d_out;
  float* part = (float*)d_ws;   // NBLK*6 floats = 48 KB, fully overwritten

  loss_main<<<NBLK, BLOCK, 0, stream>>>(trig, valp, clog, wscore, live, cid,
                                        ofire, ocan, ovalid, oshw, ocid, part);
  loss_finalize<<<1, BLOCK, 0, stream>>>(part, out);
}